// Round 6
// baseline (376.285 us; speedup 1.0000x reference)
//
#include <hip/hip_runtime.h>
#include <math.h>
#include <stdint.h>

#define D_MODEL 1024
#define NUM_HEADS 16
#define HEAD_SIZE 64
#define SEQ_T 2048

typedef __bf16 bf16;
typedef __bf16 bf16x8 __attribute__((ext_vector_type(8)));
typedef float f32x4 __attribute__((ext_vector_type(4)));

__device__ __forceinline__ void gld_lds16(const bf16* g, bf16* l) {
    __builtin_amdgcn_global_load_lds(
        (__attribute__((address_space(1))) void*)(const_cast<bf16*>(g)),
        (__attribute__((address_space(3))) void*)(l), 16, 0, 0);
}

struct __align__(8) b4pack { bf16 v[4]; };

// ---------------- fused f32 -> bf16 cast of all 4 weight matrices ----------------
__global__ __launch_bounds__(256) void cast_all_weights(const float* __restrict__ s0, bf16* __restrict__ d0, int n0,
                                                        const float* __restrict__ s1, bf16* __restrict__ d1, int n1,
                                                        const float* __restrict__ s2, bf16* __restrict__ d2, int n2,
                                                        const float* __restrict__ s3, bf16* __restrict__ d3, int n3) {
    int i = (blockIdx.x * 256 + threadIdx.x) * 4;
    const float* src;
    bf16* dst;
    if (i < n0) { src = s0; dst = d0; }
    else if (i < n0 + n1) { i -= n0; src = s1; dst = d1; }
    else if (i < n0 + n1 + n2) { i -= n0 + n1; src = s2; dst = d2; }
    else { i -= n0 + n1 + n2; if (i >= n3) return; src = s3; dst = d3; }
    float4 v = *(const float4*)(src + i);
    b4pack o;
    o.v[0] = (bf16)v.x; o.v[1] = (bf16)v.y; o.v[2] = (bf16)v.z; o.v[3] = (bf16)v.w;
    *(b4pack*)(dst + i) = o;
}

// ---------------- fused RMSNorm + RoPE ----------------
__global__ __launch_bounds__(256) void rmsnorm_rope_kernel(const float* __restrict__ x,
                                                           const float* __restrict__ scale,
                                                           bf16* __restrict__ xn,
                                                           bf16* __restrict__ rp, int T) {
    __shared__ float red[4];
    int row = blockIdx.x;
    int t = row % T;
    const float* xp = x + (size_t)row * D_MODEL;
    int tid = threadIdx.x;
    float4 xv = *(const float4*)(xp + tid * 4);
    float s = xv.x * xv.x + xv.y * xv.y + xv.z * xv.z + xv.w * xv.w;
    for (int off = 32; off; off >>= 1) s += __shfl_down(s, off);
    if ((tid & 63) == 0) red[tid >> 6] = s;
    __syncthreads();
    if (tid == 0) red[0] = red[0] + red[1] + red[2] + red[3];
    __syncthreads();
    float inv = rsqrtf(red[0] * (1.0f / D_MODEL) + 1e-6f);
    float4 sc = *(const float4*)(scale + tid * 4);
    float n0 = xv.x * inv * sc.x, n1 = xv.y * inv * sc.y;
    float n2 = xv.z * inv * sc.z, n3 = xv.w * inv * sc.w;
    b4pack pn;
    pn.v[0] = (bf16)n0; pn.v[1] = (bf16)n1; pn.v[2] = (bf16)n2; pn.v[3] = (bf16)n3;
    *(b4pack*)(xn + (size_t)row * D_MODEL + tid * 4) = pn;
    int p0 = 2 * tid;
    float th0 = expf(-0.2878231366242557f * (float)(p0 & 31));        // ln(10000)/32
    float th1 = expf(-0.2878231366242557f * (float)((p0 + 1) & 31));
    float s0, c0, s1, c1;
    sincosf((float)t * th0, &s0, &c0);
    sincosf((float)t * th1, &s1, &c1);
    b4pack pr;
    pr.v[0] = (bf16)(n0 * c0 - n1 * s0);
    pr.v[1] = (bf16)(n1 * c0 + n0 * s0);
    pr.v[2] = (bf16)(n2 * c1 - n3 * s1);
    pr.v[3] = (bf16)(n3 * c1 + n2 * s1);
    *(b4pack*)(rp + (size_t)row * D_MODEL + tid * 4) = pr;
}

// ---------------- RMSNorm only ----------------
__global__ __launch_bounds__(256) void rmsnorm_kernel(const float* __restrict__ x,
                                                      const float* __restrict__ scale,
                                                      bf16* __restrict__ out) {
    __shared__ float red[4];
    int row = blockIdx.x;
    const float* xp = x + (size_t)row * D_MODEL;
    bf16* op = out + (size_t)row * D_MODEL;
    int tid = threadIdx.x;
    float s = 0.f;
    for (int i = tid; i < D_MODEL; i += 256) { float v = xp[i]; s += v * v; }
    for (int off = 32; off; off >>= 1) s += __shfl_down(s, off);
    if ((tid & 63) == 0) red[tid >> 6] = s;
    __syncthreads();
    if (tid == 0) red[0] = red[0] + red[1] + red[2] + red[3];
    __syncthreads();
    float inv = rsqrtf(red[0] * (1.0f / D_MODEL) + 1e-6f);
    for (int i = tid; i < D_MODEL; i += 256) op[i] = (bf16)(xp[i] * inv * scale[i]);
}

// -------- bf16 MFMA GEMM, 128x128 tile, BK=64, 3-buffer 2-ahead pipeline --------
// R5 post-mortem: 2-phase (1-deep prefetch) left ~50% of each K-step stalled --
// vmcnt wait covers only ONE step of compute (~620cy) vs load latency ~900cy+.
// Fix (T4 formula N = loads/tile x tiles-in-flight): 3 rotating LDS buffers,
// stage tile t+2 each iter, s_waitcnt vmcnt(16) steady / 8 penultimate / 0 last.
// 96 KB LDS -> 1 block/CU; hiding moves from TLP into the 2-step-deep pipeline
// (issue->wait distance ~1300cy > HBM latency).
template <int ACT, int ADD, int OUT_BF16, int VT>
__global__ __launch_bounds__(256) void gemm_bf16(const bf16* __restrict__ A,
                                                 const bf16* __restrict__ A2, int splitN,
                                                 const bf16* __restrict__ W,
                                                 const float* __restrict__ bias,
                                                 float* __restrict__ Cf,
                                                 bf16* __restrict__ Cb,
                                                 bf16* __restrict__ Vtp, int Tlen,
                                                 int M, int N, int K) {
    __shared__ __align__(16) bf16 As[3][128 * 64];   // 3 x 16 KB
    __shared__ __align__(16) bf16 Bs[3][128 * 64];   // 3 x 16 KB
    int tid = threadIdx.x;
    int m0 = blockIdx.y * 128, n0 = blockIdx.x * 128;
    const bf16* Ag = (n0 < splitN) ? A : A2;

    int lane = tid & 63, w = tid >> 6;
    int wm = w >> 1, wn = w & 1;
    int lm = lane & 15, quad = lane >> 4;
    int lm7 = lm & 7;

    f32x4 acc[4][4];
#pragma unroll
    for (int i = 0; i < 4; i++)
#pragma unroll
        for (int j = 0; j < 4; j++)
#pragma unroll
            for (int r = 0; r < 4; r++) acc[i][j][r] = 0.f;

    int nt = K >> 6;

    auto stage = [&](int buf, int k0) {
#pragma unroll
        for (int i = 0; i < 4; i++) {
            int cch = tid + 256 * i;
            int r = cch >> 3, cc = (cch & 7) ^ (r & 7);
            gld_lds16(Ag + (size_t)(m0 + r) * K + k0 + cc * 8, &As[buf][0] + cch * 8);
            gld_lds16(W  + (size_t)(n0 + r) * K + k0 + cc * 8, &Bs[buf][0] + cch * 8);
        }
    };

    // prologue: stage tiles 0 and 1
    stage(0, 0);
    if (nt > 1) stage(1, 64);

    int cur = 0, nx1 = 1, nx2 = 2;
    for (int t = 0; t < nt; ++t) {
        if (t + 2 < nt) {
            stage(nx2, (t + 2) << 6);
            asm volatile("s_waitcnt vmcnt(16)" ::: "memory");  // tile t landed
        } else if (t + 1 < nt) {
            asm volatile("s_waitcnt vmcnt(8)" ::: "memory");
        } else {
            asm volatile("s_waitcnt vmcnt(0)" ::: "memory");
        }
        __builtin_amdgcn_s_barrier();

        const bf16* as = &As[cur][0];
        const bf16* bs = &Bs[cur][0];
        bf16x8 af[4][2], bfr[4][2];
#pragma unroll
        for (int i = 0; i < 4; i++) {
            int row = wm * 64 + i * 16 + lm;
#pragma unroll
            for (int h2 = 0; h2 < 2; h2++)
                af[i][h2] = *(const bf16x8*)&as[row * 64 + ((h2 * 4 + quad) ^ lm7) * 8];
        }
#pragma unroll
        for (int j = 0; j < 4; j++) {
            int row = wn * 64 + j * 16 + lm;
#pragma unroll
            for (int h2 = 0; h2 < 2; h2++)
                bfr[j][h2] = *(const bf16x8*)&bs[row * 64 + ((h2 * 4 + quad) ^ lm7) * 8];
        }
#pragma unroll
        for (int i = 0; i < 4; i++)
#pragma unroll
            for (int j = 0; j < 4; j++) {
                acc[i][j] = __builtin_amdgcn_mfma_f32_16x16x32_bf16(af[i][0], bfr[j][0], acc[i][j], 0, 0, 0);
                acc[i][j] = __builtin_amdgcn_mfma_f32_16x16x32_bf16(af[i][1], bfr[j][1], acc[i][j], 0, 0, 0);
            }
        asm volatile("" ::: "memory");   // keep ds_reads/MFMA above the barrier
        __builtin_amdgcn_s_barrier();    // protect buffers from next stage
        int tmp = cur; cur = nx1; nx1 = nx2; nx2 = tmp;
    }

    if (VT && n0 >= 2 * D_MODEL) {
#pragma unroll
        for (int j = 0; j < 4; j++) {
            int col = n0 + wn * 64 + j * 16 + lm;
            int dimg = col - 2 * D_MODEL;
            float bv = bias[col];
#pragma unroll
            for (int i = 0; i < 4; i++) {
                int row0 = m0 + wm * 64 + i * 16 + quad * 4;
                int bb = row0 / Tlen, t0 = row0 % Tlen;
                b4pack pk;
#pragma unroll
                for (int r = 0; r < 4; r++) pk.v[r] = (bf16)(acc[i][j][r] + bv);
                *(b4pack*)(Vtp + ((size_t)bb * D_MODEL + dimg) * Tlen + t0) = pk;
            }
        }
        return;
    }

#pragma unroll
    for (int j = 0; j < 4; j++) {
        int col = n0 + wn * 64 + j * 16 + lm;
        float bv = bias[col];
#pragma unroll
        for (int i = 0; i < 4; i++) {
#pragma unroll
            for (int r = 0; r < 4; r++) {
                int row = m0 + wm * 64 + i * 16 + quad * 4 + r;
                float v = acc[i][j][r] + bv;
                if (ACT == 1) v = v / (1.f + __expf(-v));
                size_t idx = (size_t)row * N + col;
                if (ADD) v += Cf[idx];
                if (OUT_BF16) Cb[idx] = (bf16)v;
                else Cf[idx] = v;
            }
        }
    }
}

// ------ skinny bf16 GEMM, 64x128 tile, BK=64, 3-buffer 2-ahead pipeline ------
// R5: 2-phase stalled ~50%/step (1-deep prefetch < load latency). 3 rotating
// buffers (72 KB, still 2 blocks/CU), stage t+2, vmcnt(12)/6/0 counted waits.
template <int ADD>
__global__ __launch_bounds__(256) void gemm_bf16_skinny2(const bf16* __restrict__ A,
                                                         const bf16* __restrict__ W,
                                                         const float* __restrict__ bias,
                                                         float* __restrict__ Cf,
                                                         int M, int N, int K) {
    __shared__ __align__(16) bf16 As[3][64 * 64];    // 3 x 8 KB
    __shared__ __align__(16) bf16 Bs[3][128 * 64];   // 3 x 16 KB
    int tid = threadIdx.x;

    int nblk = gridDim.x;
    int q = nblk >> 3;
    int swz = (blockIdx.x & 7) * q + (blockIdx.x >> 3);
    int nb = swz & 7;          // N/128 == 8
    int mb = swz >> 3;
    int m0 = mb * 64, n0 = nb * 128;

    int lane = tid & 63, w = tid >> 6;
    int wm = w >> 1, wn = w & 1;          // 2x2 wave grid: 32 rows x 64 cols each
    int lm = lane & 15, quad = lane >> 4;
    int lm7 = lm & 7;

    int ar0 = tid >> 3, ac0 = (tid & 7) ^ (ar0 & 7);                 // A chunk 0
    int t1 = tid + 256;
    int ar1 = t1 >> 3, ac1 = (t1 & 7) ^ (ar1 & 7);                  // A chunk 1

    f32x4 acc[2][4];
#pragma unroll
    for (int i = 0; i < 2; i++)
#pragma unroll
        for (int j = 0; j < 4; j++)
#pragma unroll
            for (int r = 0; r < 4; r++) acc[i][j][r] = 0.f;

    int nt = K >> 6;

    auto stage = [&](int buf, int k0) {
        gld_lds16(A + (size_t)(m0 + ar0) * K + k0 + ac0 * 8, &As[buf][0] + tid * 8);
        gld_lds16(A + (size_t)(m0 + ar1) * K + k0 + ac1 * 8, &As[buf][0] + t1 * 8);
#pragma unroll
        for (int i = 0; i < 4; i++) {
            int c = tid + 256 * i;
            int r = c >> 3, cc = (c & 7) ^ (r & 7);
            gld_lds16(W + (size_t)(n0 + r) * K + k0 + cc * 8, &Bs[buf][0] + c * 8);
        }
    };

    // prologue: stage tiles 0 and 1
    stage(0, 0);
    if (nt > 1) stage(1, 64);

    int cur = 0, nx1 = 1, nx2 = 2;
    for (int t = 0; t < nt; ++t) {
        if (t + 2 < nt) {
            stage(nx2, (t + 2) << 6);
            asm volatile("s_waitcnt vmcnt(12)" ::: "memory");  // tile t landed
        } else if (t + 1 < nt) {
            asm volatile("s_waitcnt vmcnt(6)" ::: "memory");
        } else {
            asm volatile("s_waitcnt vmcnt(0)" ::: "memory");
        }
        __builtin_amdgcn_s_barrier();

        const bf16* as = &As[cur][0];
        const bf16* bs = &Bs[cur][0];
        bf16x8 af[2][2], bfr[4][2];
#pragma unroll
        for (int i = 0; i < 2; i++) {
            int row = wm * 32 + i * 16 + lm;
#pragma unroll
            for (int h = 0; h < 2; h++)
                af[i][h] = *(const bf16x8*)&as[row * 64 + ((h * 4 + quad) ^ lm7) * 8];
        }
#pragma unroll
        for (int j = 0; j < 4; j++) {
            int row = wn * 64 + j * 16 + lm;
#pragma unroll
            for (int h = 0; h < 2; h++)
                bfr[j][h] = *(const bf16x8*)&bs[row * 64 + ((h * 4 + quad) ^ lm7) * 8];
        }
#pragma unroll
        for (int i = 0; i < 2; i++)
#pragma unroll
            for (int j = 0; j < 4; j++) {
                acc[i][j] = __builtin_amdgcn_mfma_f32_16x16x32_bf16(af[i][0], bfr[j][0], acc[i][j], 0, 0, 0);
                acc[i][j] = __builtin_amdgcn_mfma_f32_16x16x32_bf16(af[i][1], bfr[j][1], acc[i][j], 0, 0, 0);
            }
        asm volatile("" ::: "memory");
        __builtin_amdgcn_s_barrier();
        int tmp = cur; cur = nx1; nx1 = nx2; nx2 = tmp;
    }

#pragma unroll
    for (int j = 0; j < 4; j++) {
        int col = n0 + wn * 64 + j * 16 + lm;
        float bv = bias[col];
#pragma unroll
        for (int i = 0; i < 2; i++) {
#pragma unroll
            for (int r = 0; r < 4; r++) {
                int row = m0 + wm * 32 + i * 16 + quad * 4 + r;
                float v = acc[i][j][r] + bv;
                size_t idx = (size_t)row * N + col;
                if (ADD) v += Cf[idx];
                Cf[idx] = v;
            }
        }
    }
}

// ------- MFMA flash attention: pair-merged blocks, fixed-base softmax -------
__global__ __launch_bounds__(256, 2) void attn_mfma_kernel(const bf16* __restrict__ QKV,
                                                           const bf16* __restrict__ Vt,
                                                           bf16* __restrict__ Og, int T) {
    __shared__ __align__(16) bf16 Ks[2][2][64 * 64];   // [buf][sub] 32 KB
    __shared__ __align__(16) bf16 Vs[2][2][64 * 64];   // 32 KB
    __shared__ __align__(16) bf16 Ps[4 * 16 * 64];     // 8 KB, per-wave XOR-swizzled P
    const int ldq = 3 * D_MODEL;
    int bidx = blockIdx.x;
    int c = bidx & 7;               // XCD id; same-bh blocks share an XCD L2
    int rest = bidx >> 3;           // [0,64)
    int p = rest & 15;              // pair id
    int bhoct = rest >> 4;          // [0,4)
    int bh = bhoct * 8 + c;
    int qtA = 31 - p, qtB = p;      // qtA 16..31, qtB 0..15
    int h = bh & (NUM_HEADS - 1), b = bh / NUM_HEADS;
    int tid = threadIdx.x;
    int w = tid >> 6, lane = tid & 63;
    int lm = lane & 15, quad = lane >> 4;
    int qrowA = qtA * 64 + w * 16, qrowB = qtB * 64 + w * 16;

    int s0 = tid, s1 = tid + 256;
    int sr0 = s0 >> 3, sc0 = (s0 & 7) ^ (sr0 & 7);
    int sr1 = s1 >> 3, sc1 = (s1 & 7) ^ (sr1 & 7);

    const bf16* QpA = QKV + ((size_t)(b * T + qrowA + lm)) * ldq + h * HEAD_SIZE + quad * 8;
    bf16x8 qfA0 = *(const bf16x8*)QpA;
    bf16x8 qfA1 = *(const bf16x8*)(QpA + 32);
    const bf16* QpB = QKV + ((size_t)(b * T + qrowB + lm)) * ldq + h * HEAD_SIZE + quad * 8;
    bf16x8 qfB0 = *(const bf16x8*)QpB;
    bf16x8 qfB1 = *(const bf16x8*)(QpB + 32);

    const bf16* Kbase = QKV + ((size_t)b * T) * ldq + D_MODEL + h * HEAD_SIZE;
    const bf16* Vbase = Vt + ((size_t)b * D_MODEL + h * HEAD_SIZE) * T;
    const float C = 0.1803368801111204f;  // 0.125 * log2(e)
    bf16* PsW = Ps + w * 16 * 64;
    int lm7 = lm & 7;

    bf16x8 ones;
#pragma unroll
    for (int i = 0; i < 8; i++) ones[i] = (bf16)1.0f;

    f32x4 oA[4], oB[4], laccA, laccB;
#pragma unroll
    for (int r = 0; r < 4; r++) {
        oA[r] = (f32x4){0.f, 0.f, 0.f, 0.f};
        oB[r] = (f32x4){0.f, 0.f, 0.f, 0.f};
        laccA[r] = 0.f; laccB[r] = 0.f;
    }

    int nktA = (qtA + 2) >> 1;   // 9..16
    int nktB = (qtB + 2) >> 1;   // 1..8 (always < nktA)

    auto stage = [&](int buf, int k0) {
        gld_lds16(Kbase + (size_t)(k0 + sr0) * ldq + sc0 * 8, &Ks[buf][0][0] + s0 * 8);
        gld_lds16(Kbase + (size_t)(k0 + sr1) * ldq + sc1 * 8, &Ks[buf][0][0] + s1 * 8);
        gld_lds16(Kbase + (size_t)(k0 + 64 + sr0) * ldq + sc0 * 8, &Ks[buf][1][0] + s0 * 8);
        gld_lds16(Kbase + (size_t)(k0 + 64 + sr1) * ldq + sc1 * 8, &Ks[buf][1][0] + s1 * 8);
        gld_lds16(Vbase + (size_t)sr0 * T + k0 + sc0 * 8, &Vs[buf][0][0] + s0 * 8);
        gld_lds16(Vbase + (size_t)sr1 * T + k0 + sc1 * 8, &Vs[buf][0][0] + s1 * 8);
        gld_lds16(Vbase + (size_t)sr0 * T + k0 + 64 + sc0 * 8, &Vs[buf][1][0] + s0 * 8);
        gld_lds16(Vbase + (size_t)sr1 * T + k0 + 64 + sc1 * 8, &Vs[buf][1][0] + s1 * 8);
    };

    auto run_tile = [&](int cur, int k0, bf16x8 qf0, bf16x8 qf1, int qrow0,
                        f32x4 (&o)[4], f32x4& lacc, bool lastmask) {
        f32x4 sa[2][4];
        __builtin_amdgcn_s_setprio(1);
#pragma unroll
        for (int u = 0; u < 2; u++) {
            const bf16* Ksu = &Ks[cur][u][0];
#pragma unroll
            for (int jb = 0; jb < 4; jb++) {
                int n = jb * 16 + lm;
                bf16x8 kf0 = *(const bf16x8*)&Ksu[(n * 8 + (quad ^ lm7)) * 8];
                bf16x8 kf1 = *(const bf16x8*)&Ksu[(n * 8 + ((quad + 4) ^ lm7)) * 8];
                f32x4 a = {0.f, 0.f, 0.f, 0.f};
                a = __builtin_amdgcn_mfma_f32_16x16x32_bf16(qf0, kf0, a, 0, 0, 0);
                a = __builtin_amdgcn_mfma_f32_16x16x32_bf16(qf1, kf1, a, 0, 0, 0);
                sa[u][jb] = a;
            }
        }
        __builtin_amdgcn_s_setprio(0);
        if (lastmask) {
#pragma unroll
            for (int u = 0; u < 2; u++)
#pragma unroll
                for (int jb = 0; jb < 4; jb++)
#pragma unroll
                    for (int r = 0; r < 4; r++)
                        if (k0 + u * 64 + jb * 16 + lm > qrow0 + quad * 4 + r)
                            sa[u][jb][r] = -3.0e38f;
        }
        // fixed-base softmax: p = exp2(s*C); masked -> exp2(-huge) == 0
#pragma unroll
        for (int u = 0; u < 2; u++) {
            const bf16* Vsu = &Vs[cur][u][0];
#pragma unroll
            for (int jb = 0; jb < 4; jb++) {
                int g = jb * 2 + (lm >> 3);
#pragma unroll
                for (int r = 0; r < 4; r++) {
                    int row = quad * 4 + r;
                    float pv = exp2f(sa[u][jb][r] * C);
                    PsW[row * 64 + ((g ^ (row & 7)) * 8) + lm7] = (bf16)pv;
                }
            }
            bf16x8 pf0 = *(const bf16x8*)&PsW[lm * 64 + ((quad ^ lm7) * 8)];
            bf16x8 pf1 = *(const bf16x8*)&PsW[lm * 64 + (((quad + 4) ^ lm7) * 8)];
            __builtin_amdgcn_s_setprio(1);
#pragma unroll
            for (int db = 0; db < 4; db++) {
                int n = db * 16 + lm;
                bf16x8 vf0 = *(const bf16x8*)&Vsu[(n * 8 + (quad ^ lm7)) * 8];
                bf16x8 vf1 = *(const bf16x8*)&Vsu[(n * 8 + ((quad + 4) ^ lm7)) * 8];
                o[db] = __builtin_amdgcn_mfma_f32_16x16x32_bf16(pf0, vf0, o[db], 0, 0, 0);
                o[db] = __builtin_amdgcn_mfma_f32_16x16x32_bf16(pf1, vf1, o[db], 0, 0, 0);
            }
            // row-sum of P on the matrix pipe: l += P @ ones
            lacc = __builtin_amdgcn_mfma_f32_16x16x32_bf16(pf0, ones, lacc, 0, 0, 0);
            lacc = __builtin_amdgcn_mfma_f32_16x16x32_bf16(pf1, ones, lacc, 0, 0, 0);
            __builtin_amdgcn_s_setprio(0);
        }
    };

    stage(0, 0);   // prologue: round 0 -> buffer 0
    for (int kt = 0; kt < nktA; kt++) {
        int cur = kt & 1;
        if (kt + 1 < nktA) {
            stage(cur ^ 1, (kt + 1) * 128);
            asm volatile("s_waitcnt vmcnt(8)" ::: "memory");  // round kt landed
        } else {
            asm volatile("s_waitcnt vmcnt(0)" ::: "memory");
        }
        __builtin_amdgcn_s_barrier();
        asm volatile("" ::: "memory");
        int k0 = kt * 128;
        run_tile(cur, k0, qfA0, qfA1, qrowA, oA, laccA, kt == nktA - 1);
        if (kt < nktB)
            run_tile(cur, k0, qfB0, qfB1, qrowB, oB, laccB, kt == nktB - 1);
        asm volatile("" ::: "memory");
        __builtin_amdgcn_s_barrier();   // protect buffers from next stage
    }

    // epilogue: O / l -> bf16, both tiles
    {
        float inv[4];
#pragma unroll
        for (int r = 0; r < 4; r++) inv[r] = 1.f / laccA[r];
        bf16* Ob = Og + ((size_t)(b * T + qrowA + quad * 4)) * D_MODEL + h * HEAD_SIZE + lm;
#pragma unroll
        for (int r = 0; r < 4; r++)
#pragma unroll
            for (int db = 0; db < 4; db++)
                Ob[(size_t)r * D_MODEL + db * 16] = (bf16)(oA[db][r] * inv[r]);
    }
    {
        float inv[4];
#pragma unroll
        for (int r = 0; r < 4; r++) inv[r] = 1.f / laccB[r];
        bf16* Ob = Og + ((size_t)(b * T + qrowB + quad * 4)) * D_MODEL + h * HEAD_SIZE + lm;
#pragma unroll
        for (int r = 0; r < 4; r++)
#pragma unroll
            for (int db = 0; db < 4; db++)
                Ob[(size_t)r * D_MODEL + db * 16] = (bf16)(oB[db][r] * inv[r]);
    }
}

extern "C" void kernel_launch(void* const* d_in, const int* in_sizes, int n_in,
                              void* d_out, int out_size, void* d_ws, size_t ws_size,
                              hipStream_t stream) {
    const float* x          = (const float*)d_in[0];
    const float* rms_scale  = (const float*)d_in[1];
    const float* in_proj_w  = (const float*)d_in[2];
    const float* in_proj_b  = (const float*)d_in[3];
    const float* out_proj_w = (const float*)d_in[4];
    const float* out_proj_b = (const float*)d_in[5];
    const float* w1         = (const float*)d_in[6];
    const float* b1         = (const float*)d_in[7];
    const float* w2         = (const float*)d_in[8];
    const float* b2         = (const float*)d_in[9];
    float* out = (float*)d_out;

    const int rows = in_sizes[0] / D_MODEL;  // 4096
    const int T = SEQ_T;
    const int B = rows / T;
    const int D = D_MODEL;

    bf16* inwb  = (bf16*)d_ws;                       // 3M
    bf16* outwb = inwb + (size_t)3 * D * D;          // 1M
    bf16* w1b   = outwb + (size_t)D * D;             // 4M
    bf16* w2b   = w1b + (size_t)4 * D * D;           // 4M
    bf16* XNb   = w2b + (size_t)4 * D * D;           // rows*D (reused as CTXb)
    bf16* RPb   = XNb + (size_t)rows * D;            // rows*D (reused as YNb)
    bf16* QKV   = RPb + (size_t)rows * D;            // rows*3D (H1b spans rows*4D)
    bf16* Vt    = QKV + (size_t)rows * 3 * D;        // rows*D  (tail of H1b region)
    bf16* CTXb  = XNb;
    bf16* YNb   = RPb;
    bf16* H1b   = QKV;

    // 0. cast all weights to bf16 (one kernel)
    {
        int n0 = 3 * D * D, n1 = D * D, n2 = 4 * D * D, n3 = 4 * D * D;
        int tot4 = (n0 + n1 + n2 + n3) / 4;
        cast_all_weights<<<(tot4 + 255) / 256, 256, 0, stream>>>(
            in_proj_w, inwb, n0, out_proj_w, outwb, n1, w1, w1b, n2, w2, w2b, n3);
    }
    // 1+2. fused rmsnorm + rope
    rmsnorm_rope_kernel<<<rows, 256, 0, stream>>>(x, rms_scale, XNb, RPb, T);
    // 3. fused QKV projection; Q/K -> QKV buffer, V -> Vt (transposed)
    {
        dim3 g(3 * D / 128, rows / 128);
        gemm_bf16<0, 0, 1, 1><<<g, 256, 0, stream>>>(RPb, XNb, 2 * D, inwb, in_proj_b,
                                                     nullptr, QKV, Vt, T, rows, 3 * D, D);
    }
    // 4. attention -> CTXb (bf16): 512 pair-merged balanced blocks, dbuf pipeline
    attn_mfma_kernel<<<B * NUM_HEADS * (T / 128), 256, 0, stream>>>(QKV, Vt, CTXb, T);
    // 5. y = CTXb @ out_proj^T + b -> d_out (fp32), 3-buffer skinny (512 blocks)
    {
        int nblk = (D / 128) * (rows / 64);
        gemm_bf16_skinny2<0><<<nblk, 256, 0, stream>>>(CTXb, outwb, out_proj_b, out,
                                                       rows, D, D);
    }
    // 6. yn = rmsnorm(y) -> bf16
    rmsnorm_kernel<<<rows, 256, 0, stream>>>(out, rms_scale, YNb);
    // 7. H1b = silu(yn @ w1^T + b1) (bf16)
    {
        dim3 g(4 * D / 128, rows / 128);
        gemm_bf16<1, 0, 1, 0><<<g, 256, 0, stream>>>(YNb, YNb, 4 * D, w1b, b1,
                                                     nullptr, H1b, nullptr, 1, rows, 4 * D, D);
    }
    // 8. out += H1b @ w2^T + b2 (fp32 residual), 3-buffer skinny (512 blocks)
    {
        int nblk = (D / 128) * (rows / 64);
        gemm_bf16_skinny2<1><<<nblk, 256, 0, stream>>>(H1b, w2b, b2, out,
                                                       rows, D, 4 * D);
    }
}

// Round 7
// 365.976 us; speedup vs baseline: 1.0282x; 1.0282x over previous
//
#include <hip/hip_runtime.h>
#include <math.h>
#include <stdint.h>

#define D_MODEL 1024
#define NUM_HEADS 16
#define HEAD_SIZE 64
#define SEQ_T 2048

typedef __bf16 bf16;
typedef __bf16 bf16x8 __attribute__((ext_vector_type(8)));
typedef float f32x4 __attribute__((ext_vector_type(4)));

__device__ __forceinline__ void gld_lds16(const bf16* g, bf16* l) {
    __builtin_amdgcn_global_load_lds(
        (__attribute__((address_space(1))) void*)(const_cast<bf16*>(g)),
        (__attribute__((address_space(3))) void*)(l), 16, 0, 0);
}

struct __align__(8) b4pack { bf16 v[4]; };

// ------- fused f32 -> bf16 cast of all 4 weight matrices + bias-init of out -------
// region 4 (R1-verified): out[row][col] = out_proj_b[col], pre-init for split-K step 5.
__global__ __launch_bounds__(256) void cast_all_weights(const float* __restrict__ s0, bf16* __restrict__ d0, int n0,
                                                        const float* __restrict__ s1, bf16* __restrict__ d1, int n1,
                                                        const float* __restrict__ s2, bf16* __restrict__ d2, int n2,
                                                        const float* __restrict__ s3, bf16* __restrict__ d3, int n3,
                                                        const float* __restrict__ bsrc, float* __restrict__ bdst, int n4) {
    int i = (blockIdx.x * 256 + threadIdx.x) * 4;
    const float* src;
    bf16* dst;
    if (i < n0) { src = s0; dst = d0; }
    else if (i < n0 + n1) { i -= n0; src = s1; dst = d1; }
    else if (i < n0 + n1 + n2) { i -= n0 + n1; src = s2; dst = d2; }
    else if (i < n0 + n1 + n2 + n3) { i -= n0 + n1 + n2; src = s3; dst = d3; }
    else {
        i -= n0 + n1 + n2 + n3;
        if (i >= n4) return;
        float4 b = *(const float4*)(bsrc + (i & (D_MODEL - 1)));
        *(float4*)(bdst + i) = b;
        return;
    }
    float4 v = *(const float4*)(src + i);
    b4pack o;
    o.v[0] = (bf16)v.x; o.v[1] = (bf16)v.y; o.v[2] = (bf16)v.z; o.v[3] = (bf16)v.w;
    *(b4pack*)(dst + i) = o;
}

// ---------------- fused RMSNorm + RoPE ----------------
__global__ __launch_bounds__(256) void rmsnorm_rope_kernel(const float* __restrict__ x,
                                                           const float* __restrict__ scale,
                                                           bf16* __restrict__ xn,
                                                           bf16* __restrict__ rp, int T) {
    __shared__ float red[4];
    int row = blockIdx.x;
    int t = row % T;
    const float* xp = x + (size_t)row * D_MODEL;
    int tid = threadIdx.x;
    float4 xv = *(const float4*)(xp + tid * 4);
    float s = xv.x * xv.x + xv.y * xv.y + xv.z * xv.z + xv.w * xv.w;
    for (int off = 32; off; off >>= 1) s += __shfl_down(s, off);
    if ((tid & 63) == 0) red[tid >> 6] = s;
    __syncthreads();
    if (tid == 0) red[0] = red[0] + red[1] + red[2] + red[3];
    __syncthreads();
    float inv = rsqrtf(red[0] * (1.0f / D_MODEL) + 1e-6f);
    float4 sc = *(const float4*)(scale + tid * 4);
    float n0 = xv.x * inv * sc.x, n1 = xv.y * inv * sc.y;
    float n2 = xv.z * inv * sc.z, n3 = xv.w * inv * sc.w;
    b4pack pn;
    pn.v[0] = (bf16)n0; pn.v[1] = (bf16)n1; pn.v[2] = (bf16)n2; pn.v[3] = (bf16)n3;
    *(b4pack*)(xn + (size_t)row * D_MODEL + tid * 4) = pn;
    int p0 = 2 * tid;
    float th0 = expf(-0.2878231366242557f * (float)(p0 & 31));        // ln(10000)/32
    float th1 = expf(-0.2878231366242557f * (float)((p0 + 1) & 31));
    float s0, c0, s1, c1;
    sincosf((float)t * th0, &s0, &c0);
    sincosf((float)t * th1, &s1, &c1);
    b4pack pr;
    pr.v[0] = (bf16)(n0 * c0 - n1 * s0);
    pr.v[1] = (bf16)(n1 * c0 + n0 * s0);
    pr.v[2] = (bf16)(n2 * c1 - n3 * s1);
    pr.v[3] = (bf16)(n3 * c1 + n2 * s1);
    *(b4pack*)(rp + (size_t)row * D_MODEL + tid * 4) = pr;
}

// ---------------- RMSNorm only ----------------
__global__ __launch_bounds__(256) void rmsnorm_kernel(const float* __restrict__ x,
                                                      const float* __restrict__ scale,
                                                      bf16* __restrict__ out) {
    __shared__ float red[4];
    int row = blockIdx.x;
    const float* xp = x + (size_t)row * D_MODEL;
    bf16* op = out + (size_t)row * D_MODEL;
    int tid = threadIdx.x;
    float s = 0.f;
    for (int i = tid; i < D_MODEL; i += 256) { float v = xp[i]; s += v * v; }
    for (int off = 32; off; off >>= 1) s += __shfl_down(s, off);
    if ((tid & 63) == 0) red[tid >> 6] = s;
    __syncthreads();
    if (tid == 0) red[0] = red[0] + red[1] + red[2] + red[3];
    __syncthreads();
    float inv = rsqrtf(red[0] * (1.0f / D_MODEL) + 1e-6f);
    for (int i = tid; i < D_MODEL; i += 256) op[i] = (bf16)(xp[i] * inv * scale[i]);
}

// -------- bf16 MFMA GEMM, 128x128 tile, BK=64, 2-phase dbuf + counted vmcnt --------
// R6 post-mortem: 3-buffer 2-ahead (96 KB LDS -> 1 block/CU = 1 wave/SIMD) REGRESSED
// (78.6us, MfmaUtil 16.4, Occ 10.5): pipeline depth cannot replace wave-level
// parallelism. REVERTED to the R5-verified 2-buffer 2-phase (64 KB, 2 blocks/CU).
// Never drop below 2 waves/SIMD for LDS-fed MFMA loops.
template <int ACT, int ADD, int OUT_BF16, int VT>
__global__ __launch_bounds__(256) void gemm_bf16(const bf16* __restrict__ A,
                                                 const bf16* __restrict__ A2, int splitN,
                                                 const bf16* __restrict__ W,
                                                 const float* __restrict__ bias,
                                                 float* __restrict__ Cf,
                                                 bf16* __restrict__ Cb,
                                                 bf16* __restrict__ Vtp, int Tlen,
                                                 int M, int N, int K) {
    __shared__ __align__(16) bf16 As[2][128 * 64];   // 2 x 16 KB
    __shared__ __align__(16) bf16 Bs[2][128 * 64];   // 2 x 16 KB
    int tid = threadIdx.x;
    int m0 = blockIdx.y * 128, n0 = blockIdx.x * 128;
    const bf16* Ag = (n0 < splitN) ? A : A2;

    int lane = tid & 63, w = tid >> 6;
    int wm = w >> 1, wn = w & 1;
    int lm = lane & 15, quad = lane >> 4;
    int lm7 = lm & 7;

    f32x4 acc[4][4];
#pragma unroll
    for (int i = 0; i < 4; i++)
#pragma unroll
        for (int j = 0; j < 4; j++)
#pragma unroll
            for (int r = 0; r < 4; r++) acc[i][j][r] = 0.f;

    int nt = K >> 6;

    // ---- prologue: stage tile 0 into buffer 0 (8 loads/thread) ----
#pragma unroll
    for (int i = 0; i < 4; i++) {
        int cch = tid + 256 * i;
        int r = cch >> 3, cc = (cch & 7) ^ (r & 7);
        gld_lds16(Ag + (size_t)(m0 + r) * K + cc * 8, &As[0][0] + cch * 8);
        gld_lds16(W  + (size_t)(n0 + r) * K + cc * 8, &Bs[0][0] + cch * 8);
    }

    for (int t = 0; t < nt; ++t) {
        int cur = t & 1;
        if (t + 1 < nt) {
            int k0 = (t + 1) << 6;
            bf16* as = &As[cur ^ 1][0];
            bf16* bs = &Bs[cur ^ 1][0];
#pragma unroll
            for (int i = 0; i < 4; i++) {
                int cch = tid + 256 * i;
                int r = cch >> 3, cc = (cch & 7) ^ (r & 7);
                gld_lds16(Ag + (size_t)(m0 + r) * K + k0 + cc * 8, as + cch * 8);
                gld_lds16(W  + (size_t)(n0 + r) * K + k0 + cc * 8, bs + cch * 8);
            }
            asm volatile("s_waitcnt vmcnt(8)" ::: "memory");  // current tile landed
        } else {
            asm volatile("s_waitcnt vmcnt(0)" ::: "memory");  // epilogue drain
        }
        __builtin_amdgcn_s_barrier();

        const bf16* as = &As[cur][0];
        const bf16* bs = &Bs[cur][0];
        bf16x8 af[4][2], bfr[4][2];
#pragma unroll
        for (int i = 0; i < 4; i++) {
            int row = wm * 64 + i * 16 + lm;
#pragma unroll
            for (int h2 = 0; h2 < 2; h2++)
                af[i][h2] = *(const bf16x8*)&as[row * 64 + ((h2 * 4 + quad) ^ lm7) * 8];
        }
#pragma unroll
        for (int j = 0; j < 4; j++) {
            int row = wn * 64 + j * 16 + lm;
#pragma unroll
            for (int h2 = 0; h2 < 2; h2++)
                bfr[j][h2] = *(const bf16x8*)&bs[row * 64 + ((h2 * 4 + quad) ^ lm7) * 8];
        }
#pragma unroll
        for (int i = 0; i < 4; i++)
#pragma unroll
            for (int j = 0; j < 4; j++) {
                acc[i][j] = __builtin_amdgcn_mfma_f32_16x16x32_bf16(af[i][0], bfr[j][0], acc[i][j], 0, 0, 0);
                acc[i][j] = __builtin_amdgcn_mfma_f32_16x16x32_bf16(af[i][1], bfr[j][1], acc[i][j], 0, 0, 0);
            }
        asm volatile("" ::: "memory");   // keep ds_reads/MFMA above the barrier
        __builtin_amdgcn_s_barrier();    // protect current buffer from next stage
    }

    if (VT && n0 >= 2 * D_MODEL) {
#pragma unroll
        for (int j = 0; j < 4; j++) {
            int col = n0 + wn * 64 + j * 16 + lm;
            int dimg = col - 2 * D_MODEL;
            float bv = bias[col];
#pragma unroll
            for (int i = 0; i < 4; i++) {
                int row0 = m0 + wm * 64 + i * 16 + quad * 4;
                int bb = row0 / Tlen, t0 = row0 % Tlen;
                b4pack pk;
#pragma unroll
                for (int r = 0; r < 4; r++) pk.v[r] = (bf16)(acc[i][j][r] + bv);
                *(b4pack*)(Vtp + ((size_t)bb * D_MODEL + dimg) * Tlen + t0) = pk;
            }
        }
        return;
    }

#pragma unroll
    for (int j = 0; j < 4; j++) {
        int col = n0 + wn * 64 + j * 16 + lm;
        float bv = bias[col];
#pragma unroll
        for (int i = 0; i < 4; i++) {
#pragma unroll
            for (int r = 0; r < 4; r++) {
                int row = m0 + wm * 64 + i * 16 + quad * 4 + r;
                float v = acc[i][j][r] + bv;
                if (ACT == 1) v = v / (1.f + __expf(-v));
                size_t idx = (size_t)row * N + col;
                if (ADD) v += Cf[idx];
                if (OUT_BF16) Cb[idx] = (bf16)v;
                else Cf[idx] = v;
            }
        }
    }
}

// -- skinny bf16 GEMM, 64x128 tile, BK=64, 2-phase dbuf + SPLIT-K x2 (atomics) --
// R5/R6 post-mortem: the skinny GEMM's occupancy is GRID-bound (512 blocks = exactly
// 2 blocks/CU); 3-buffer depth was ~neutral. Split-K x2 -> 1024 blocks, 48 KB LDS ->
// 3 blocks/CU resident (3 waves/SIMD, +50% TLP), half the K-chain per block.
// Epilogue: fp32 unsafeAtomicAdd (commutative; R1 harness-verified). BIAS0: split 0
// adds bias (step 8); step 5's bias pre-initialized into out by cast region 4.
// XCD swizzle order: n fastest, then m, then split -> each XCD gets a contiguous
// (m-chunk, split) with all 8 n-blocks: W-split chunk L2-resident, A fetched once.
template <int BIAS0, int SPLIT>
__global__ __launch_bounds__(256) void gemm_bf16_skinny_sk(const bf16* __restrict__ A,
                                                           const bf16* __restrict__ W,
                                                           const float* __restrict__ bias,
                                                           float* __restrict__ Cf,
                                                           int M, int N, int K) {
    __shared__ __align__(16) bf16 As[2][64 * 64];    // 2 x 8 KB
    __shared__ __align__(16) bf16 Bs[2][128 * 64];   // 2 x 16 KB
    int tid = threadIdx.x;

    int nblk = gridDim.x;
    int q = nblk >> 3;
    int swz = (blockIdx.x & 7) * q + (blockIdx.x >> 3);
    int nb = swz & 7;                  // N/128 == 8
    int rem = swz >> 3;
    int mblocks = M >> 6;
    int mb = rem % mblocks;
    int sp = rem / mblocks;
    int m0 = mb * 64, n0 = nb * 128;
    int kc = K / SPLIT;
    int kbeg = sp * kc;

    int lane = tid & 63, w = tid >> 6;
    int wm = w >> 1, wn = w & 1;          // 2x2 wave grid: 32 rows x 64 cols each
    int lm = lane & 15, quad = lane >> 4;
    int lm7 = lm & 7;

    int ar0 = tid >> 3, ac0 = (tid & 7) ^ (ar0 & 7);                 // A chunk 0
    int t1 = tid + 256;
    int ar1 = t1 >> 3, ac1 = (t1 & 7) ^ (ar1 & 7);                  // A chunk 1

    f32x4 acc[2][4];
#pragma unroll
    for (int i = 0; i < 2; i++)
#pragma unroll
        for (int j = 0; j < 4; j++)
#pragma unroll
            for (int r = 0; r < 4; r++) acc[i][j][r] = 0.f;

    int nt = kc >> 6;

    {
        gld_lds16(A + (size_t)(m0 + ar0) * K + kbeg + ac0 * 8, &As[0][0] + tid * 8);
        gld_lds16(A + (size_t)(m0 + ar1) * K + kbeg + ac1 * 8, &As[0][0] + t1 * 8);
#pragma unroll
        for (int i = 0; i < 4; i++) {
            int c = tid + 256 * i;
            int r = c >> 3, cc = (c & 7) ^ (r & 7);
            gld_lds16(W + (size_t)(n0 + r) * K + kbeg + cc * 8, &Bs[0][0] + c * 8);
        }
    }

    for (int t = 0; t < nt; ++t) {
        int cur = t & 1;
        if (t + 1 < nt) {
            int k0 = kbeg + ((t + 1) << 6);
            bf16* as = &As[cur ^ 1][0];
            bf16* bs = &Bs[cur ^ 1][0];
            gld_lds16(A + (size_t)(m0 + ar0) * K + k0 + ac0 * 8, as + tid * 8);
            gld_lds16(A + (size_t)(m0 + ar1) * K + k0 + ac1 * 8, as + t1 * 8);
#pragma unroll
            for (int i = 0; i < 4; i++) {
                int c = tid + 256 * i;
                int r = c >> 3, cc = (c & 7) ^ (r & 7);
                gld_lds16(W + (size_t)(n0 + r) * K + k0 + cc * 8, bs + c * 8);
            }
            asm volatile("s_waitcnt vmcnt(6)" ::: "memory");
        } else {
            asm volatile("s_waitcnt vmcnt(0)" ::: "memory");
        }
        __builtin_amdgcn_s_barrier();

        const bf16* as = &As[cur][0];
        const bf16* bs = &Bs[cur][0];
        bf16x8 af[2][2], bfr[4][2];
#pragma unroll
        for (int i = 0; i < 2; i++) {
            int row = wm * 32 + i * 16 + lm;
#pragma unroll
            for (int h = 0; h < 2; h++)
                af[i][h] = *(const bf16x8*)&as[row * 64 + ((h * 4 + quad) ^ lm7) * 8];
        }
#pragma unroll
        for (int j = 0; j < 4; j++) {
            int row = wn * 64 + j * 16 + lm;
#pragma unroll
            for (int h = 0; h < 2; h++)
                bfr[j][h] = *(const bf16x8*)&bs[row * 64 + ((h * 4 + quad) ^ lm7) * 8];
        }
#pragma unroll
        for (int i = 0; i < 2; i++)
#pragma unroll
            for (int j = 0; j < 4; j++) {
                acc[i][j] = __builtin_amdgcn_mfma_f32_16x16x32_bf16(af[i][0], bfr[j][0], acc[i][j], 0, 0, 0);
                acc[i][j] = __builtin_amdgcn_mfma_f32_16x16x32_bf16(af[i][1], bfr[j][1], acc[i][j], 0, 0, 0);
            }
        asm volatile("" ::: "memory");
        __builtin_amdgcn_s_barrier();
    }

#pragma unroll
    for (int j = 0; j < 4; j++) {
        int col = n0 + wn * 64 + j * 16 + lm;
        float bv = (BIAS0 && sp == 0) ? bias[col] : 0.f;
#pragma unroll
        for (int i = 0; i < 2; i++) {
#pragma unroll
            for (int r = 0; r < 4; r++) {
                int row = m0 + wm * 32 + i * 16 + quad * 4 + r;
                unsafeAtomicAdd(Cf + (size_t)row * N + col, acc[i][j][r] + bv);
            }
        }
    }
}

// ------- MFMA flash attention: pair-merged blocks, fixed-base softmax -------
__global__ __launch_bounds__(256, 2) void attn_mfma_kernel(const bf16* __restrict__ QKV,
                                                           const bf16* __restrict__ Vt,
                                                           bf16* __restrict__ Og, int T) {
    __shared__ __align__(16) bf16 Ks[2][2][64 * 64];   // [buf][sub] 32 KB
    __shared__ __align__(16) bf16 Vs[2][2][64 * 64];   // 32 KB
    __shared__ __align__(16) bf16 Ps[4 * 16 * 64];     // 8 KB, per-wave XOR-swizzled P
    const int ldq = 3 * D_MODEL;
    int bidx = blockIdx.x;
    int c = bidx & 7;               // XCD id; same-bh blocks share an XCD L2
    int rest = bidx >> 3;           // [0,64)
    int p = rest & 15;              // pair id
    int bhoct = rest >> 4;          // [0,4)
    int bh = bhoct * 8 + c;
    int qtA = 31 - p, qtB = p;      // qtA 16..31, qtB 0..15
    int h = bh & (NUM_HEADS - 1), b = bh / NUM_HEADS;
    int tid = threadIdx.x;
    int w = tid >> 6, lane = tid & 63;
    int lm = lane & 15, quad = lane >> 4;
    int qrowA = qtA * 64 + w * 16, qrowB = qtB * 64 + w * 16;

    int s0 = tid, s1 = tid + 256;
    int sr0 = s0 >> 3, sc0 = (s0 & 7) ^ (sr0 & 7);
    int sr1 = s1 >> 3, sc1 = (s1 & 7) ^ (sr1 & 7);

    const bf16* QpA = QKV + ((size_t)(b * T + qrowA + lm)) * ldq + h * HEAD_SIZE + quad * 8;
    bf16x8 qfA0 = *(const bf16x8*)QpA;
    bf16x8 qfA1 = *(const bf16x8*)(QpA + 32);
    const bf16* QpB = QKV + ((size_t)(b * T + qrowB + lm)) * ldq + h * HEAD_SIZE + quad * 8;
    bf16x8 qfB0 = *(const bf16x8*)QpB;
    bf16x8 qfB1 = *(const bf16x8*)(QpB + 32);

    const bf16* Kbase = QKV + ((size_t)b * T) * ldq + D_MODEL + h * HEAD_SIZE;
    const bf16* Vbase = Vt + ((size_t)b * D_MODEL + h * HEAD_SIZE) * T;
    const float C = 0.1803368801111204f;  // 0.125 * log2(e)
    bf16* PsW = Ps + w * 16 * 64;
    int lm7 = lm & 7;

    bf16x8 ones;
#pragma unroll
    for (int i = 0; i < 8; i++) ones[i] = (bf16)1.0f;

    f32x4 oA[4], oB[4], laccA, laccB;
#pragma unroll
    for (int r = 0; r < 4; r++) {
        oA[r] = (f32x4){0.f, 0.f, 0.f, 0.f};
        oB[r] = (f32x4){0.f, 0.f, 0.f, 0.f};
        laccA[r] = 0.f; laccB[r] = 0.f;
    }

    int nktA = (qtA + 2) >> 1;   // 9..16
    int nktB = (qtB + 2) >> 1;   // 1..8 (always < nktA)

    auto stage = [&](int buf, int k0) {
        gld_lds16(Kbase + (size_t)(k0 + sr0) * ldq + sc0 * 8, &Ks[buf][0][0] + s0 * 8);
        gld_lds16(Kbase + (size_t)(k0 + sr1) * ldq + sc1 * 8, &Ks[buf][0][0] + s1 * 8);
        gld_lds16(Kbase + (size_t)(k0 + 64 + sr0) * ldq + sc0 * 8, &Ks[buf][1][0] + s0 * 8);
        gld_lds16(Kbase + (size_t)(k0 + 64 + sr1) * ldq + sc1 * 8, &Ks[buf][1][0] + s1 * 8);
        gld_lds16(Vbase + (size_t)sr0 * T + k0 + sc0 * 8, &Vs[buf][0][0] + s0 * 8);
        gld_lds16(Vbase + (size_t)sr1 * T + k0 + sc1 * 8, &Vs[buf][0][0] + s1 * 8);
        gld_lds16(Vbase + (size_t)sr0 * T + k0 + 64 + sc0 * 8, &Vs[buf][1][0] + s0 * 8);
        gld_lds16(Vbase + (size_t)sr1 * T + k0 + 64 + sc1 * 8, &Vs[buf][1][0] + s1 * 8);
    };

    auto run_tile = [&](int cur, int k0, bf16x8 qf0, bf16x8 qf1, int qrow0,
                        f32x4 (&o)[4], f32x4& lacc, bool lastmask) {
        f32x4 sa[2][4];
        __builtin_amdgcn_s_setprio(1);
#pragma unroll
        for (int u = 0; u < 2; u++) {
            const bf16* Ksu = &Ks[cur][u][0];
#pragma unroll
            for (int jb = 0; jb < 4; jb++) {
                int n = jb * 16 + lm;
                bf16x8 kf0 = *(const bf16x8*)&Ksu[(n * 8 + (quad ^ lm7)) * 8];
                bf16x8 kf1 = *(const bf16x8*)&Ksu[(n * 8 + ((quad + 4) ^ lm7)) * 8];
                f32x4 a = {0.f, 0.f, 0.f, 0.f};
                a = __builtin_amdgcn_mfma_f32_16x16x32_bf16(qf0, kf0, a, 0, 0, 0);
                a = __builtin_amdgcn_mfma_f32_16x16x32_bf16(qf1, kf1, a, 0, 0, 0);
                sa[u][jb] = a;
            }
        }
        __builtin_amdgcn_s_setprio(0);
        if (lastmask) {
#pragma unroll
            for (int u = 0; u < 2; u++)
#pragma unroll
                for (int jb = 0; jb < 4; jb++)
#pragma unroll
                    for (int r = 0; r < 4; r++)
                        if (k0 + u * 64 + jb * 16 + lm > qrow0 + quad * 4 + r)
                            sa[u][jb][r] = -3.0e38f;
        }
        // fixed-base softmax: p = exp2(s*C); masked -> exp2(-huge) == 0
#pragma unroll
        for (int u = 0; u < 2; u++) {
            const bf16* Vsu = &Vs[cur][u][0];
#pragma unroll
            for (int jb = 0; jb < 4; jb++) {
                int g = jb * 2 + (lm >> 3);
#pragma unroll
                for (int r = 0; r < 4; r++) {
                    int row = quad * 4 + r;
                    float pv = exp2f(sa[u][jb][r] * C);
                    PsW[row * 64 + ((g ^ (row & 7)) * 8) + lm7] = (bf16)pv;
                }
            }
            bf16x8 pf0 = *(const bf16x8*)&PsW[lm * 64 + ((quad ^ lm7) * 8)];
            bf16x8 pf1 = *(const bf16x8*)&PsW[lm * 64 + (((quad + 4) ^ lm7) * 8)];
            __builtin_amdgcn_s_setprio(1);
#pragma unroll
            for (int db = 0; db < 4; db++) {
                int n = db * 16 + lm;
                bf16x8 vf0 = *(const bf16x8*)&Vsu[(n * 8 + (quad ^ lm7)) * 8];
                bf16x8 vf1 = *(const bf16x8*)&Vsu[(n * 8 + ((quad + 4) ^ lm7)) * 8];
                o[db] = __builtin_amdgcn_mfma_f32_16x16x32_bf16(pf0, vf0, o[db], 0, 0, 0);
                o[db] = __builtin_amdgcn_mfma_f32_16x16x32_bf16(pf1, vf1, o[db], 0, 0, 0);
            }
            // row-sum of P on the matrix pipe: l += P @ ones
            lacc = __builtin_amdgcn_mfma_f32_16x16x32_bf16(pf0, ones, lacc, 0, 0, 0);
            lacc = __builtin_amdgcn_mfma_f32_16x16x32_bf16(pf1, ones, lacc, 0, 0, 0);
            __builtin_amdgcn_s_setprio(0);
        }
    };

    stage(0, 0);   // prologue: round 0 -> buffer 0
    for (int kt = 0; kt < nktA; kt++) {
        int cur = kt & 1;
        if (kt + 1 < nktA) {
            stage(cur ^ 1, (kt + 1) * 128);
            asm volatile("s_waitcnt vmcnt(8)" ::: "memory");  // round kt landed
        } else {
            asm volatile("s_waitcnt vmcnt(0)" ::: "memory");
        }
        __builtin_amdgcn_s_barrier();
        asm volatile("" ::: "memory");
        int k0 = kt * 128;
        run_tile(cur, k0, qfA0, qfA1, qrowA, oA, laccA, kt == nktA - 1);
        if (kt < nktB)
            run_tile(cur, k0, qfB0, qfB1, qrowB, oB, laccB, kt == nktB - 1);
        asm volatile("" ::: "memory");
        __builtin_amdgcn_s_barrier();   // protect buffers from next stage
    }

    // epilogue: O / l -> bf16, both tiles
    {
        float inv[4];
#pragma unroll
        for (int r = 0; r < 4; r++) inv[r] = 1.f / laccA[r];
        bf16* Ob = Og + ((size_t)(b * T + qrowA + quad * 4)) * D_MODEL + h * HEAD_SIZE + lm;
#pragma unroll
        for (int r = 0; r < 4; r++)
#pragma unroll
            for (int db = 0; db < 4; db++)
                Ob[(size_t)r * D_MODEL + db * 16] = (bf16)(oA[db][r] * inv[r]);
    }
    {
        float inv[4];
#pragma unroll
        for (int r = 0; r < 4; r++) inv[r] = 1.f / laccB[r];
        bf16* Ob = Og + ((size_t)(b * T + qrowB + quad * 4)) * D_MODEL + h * HEAD_SIZE + lm;
#pragma unroll
        for (int r = 0; r < 4; r++)
#pragma unroll
            for (int db = 0; db < 4; db++)
                Ob[(size_t)r * D_MODEL + db * 16] = (bf16)(oB[db][r] * inv[r]);
    }
}

extern "C" void kernel_launch(void* const* d_in, const int* in_sizes, int n_in,
                              void* d_out, int out_size, void* d_ws, size_t ws_size,
                              hipStream_t stream) {
    const float* x          = (const float*)d_in[0];
    const float* rms_scale  = (const float*)d_in[1];
    const float* in_proj_w  = (const float*)d_in[2];
    const float* in_proj_b  = (const float*)d_in[3];
    const float* out_proj_w = (const float*)d_in[4];
    const float* out_proj_b = (const float*)d_in[5];
    const float* w1         = (const float*)d_in[6];
    const float* b1         = (const float*)d_in[7];
    const float* w2         = (const float*)d_in[8];
    const float* b2         = (const float*)d_in[9];
    float* out = (float*)d_out;

    const int rows = in_sizes[0] / D_MODEL;  // 4096
    const int T = SEQ_T;
    const int B = rows / T;
    const int D = D_MODEL;

    bf16* inwb  = (bf16*)d_ws;                       // 3M
    bf16* outwb = inwb + (size_t)3 * D * D;          // 1M
    bf16* w1b   = outwb + (size_t)D * D;             // 4M
    bf16* w2b   = w1b + (size_t)4 * D * D;           // 4M
    bf16* XNb   = w2b + (size_t)4 * D * D;           // rows*D (reused as CTXb)
    bf16* RPb   = XNb + (size_t)rows * D;            // rows*D (reused as YNb)
    bf16* QKV   = RPb + (size_t)rows * D;            // rows*3D (H1b spans rows*4D)
    bf16* Vt    = QKV + (size_t)rows * 3 * D;        // rows*D  (tail of H1b region)
    bf16* CTXb  = XNb;
    bf16* YNb   = RPb;
    bf16* H1b   = QKV;

    // 0. cast all weights to bf16 + pre-init out with out_proj bias (one kernel)
    {
        int n0 = 3 * D * D, n1 = D * D, n2 = 4 * D * D, n3 = 4 * D * D;
        int n4 = rows * D;
        int tot4 = (n0 + n1 + n2 + n3 + n4) / 4;
        cast_all_weights<<<(tot4 + 255) / 256, 256, 0, stream>>>(
            in_proj_w, inwb, n0, out_proj_w, outwb, n1, w1, w1b, n2, w2, w2b, n3,
            out_proj_b, out, n4);
    }
    // 1+2. fused rmsnorm + rope
    rmsnorm_rope_kernel<<<rows, 256, 0, stream>>>(x, rms_scale, XNb, RPb, T);
    // 3. fused QKV projection; Q/K -> QKV buffer, V -> Vt (transposed)
    {
        dim3 g(3 * D / 128, rows / 128);
        gemm_bf16<0, 0, 1, 1><<<g, 256, 0, stream>>>(RPb, XNb, 2 * D, inwb, in_proj_b,
                                                     nullptr, QKV, Vt, T, rows, 3 * D, D);
    }
    // 4. attention -> CTXb (bf16): 512 pair-merged balanced blocks, dbuf pipeline
    attn_mfma_kernel<<<B * NUM_HEADS * (T / 128), 256, 0, stream>>>(QKV, Vt, CTXb, T);
    // 5. out (= bias) += CTXb @ out_proj^T, split-K x2 atomic, 1024 blocks (3/CU)
    {
        int nblk = 2 * (rows / 64) * (D / 128);
        gemm_bf16_skinny_sk<0, 2><<<nblk, 256, 0, stream>>>(CTXb, outwb, out_proj_b,
                                                            out, rows, D, D);
    }
    // 6. yn = rmsnorm(y) -> bf16
    rmsnorm_kernel<<<rows, 256, 0, stream>>>(out, rms_scale, YNb);
    // 7. H1b = silu(yn @ w1^T + b1) (bf16)
    {
        dim3 g(4 * D / 128, rows / 128);
        gemm_bf16<1, 0, 1, 0><<<g, 256, 0, stream>>>(YNb, YNb, 4 * D, w1b, b1,
                                                     nullptr, H1b, nullptr, 1, rows, 4 * D, D);
    }
    // 8. out += H1b @ w2^T + b2 (split 0 adds bias), split-K x2 atomic, 1024 blocks
    {
        int nblk = 2 * (rows / 64) * (D / 128);
        gemm_bf16_skinny_sk<1, 2><<<nblk, 256, 0, stream>>>(H1b, w2b, b2,
                                                            out, rows, D, 4 * D);
    }
}

// Round 8
// 327.136 us; speedup vs baseline: 1.1502x; 1.1187x over previous
//
#include <hip/hip_runtime.h>
#include <math.h>
#include <stdint.h>

#define D_MODEL 1024
#define NUM_HEADS 16
#define HEAD_SIZE 64
#define SEQ_T 2048

typedef __bf16 bf16;
typedef __bf16 bf16x8 __attribute__((ext_vector_type(8)));
typedef float f32x4 __attribute__((ext_vector_type(4)));

__device__ __forceinline__ void gld_lds16(const bf16* g, bf16* l) {
    __builtin_amdgcn_global_load_lds(
        (__attribute__((address_space(1))) void*)(const_cast<bf16*>(g)),
        (__attribute__((address_space(3))) void*)(l), 16, 0, 0);
}

struct __align__(8) b4pack { bf16 v[4]; };

// ---------------- fused f32 -> bf16 cast of all 4 weight matrices ----------------
__global__ __launch_bounds__(256) void cast_all_weights(const float* __restrict__ s0, bf16* __restrict__ d0, int n0,
                                                        const float* __restrict__ s1, bf16* __restrict__ d1, int n1,
                                                        const float* __restrict__ s2, bf16* __restrict__ d2, int n2,
                                                        const float* __restrict__ s3, bf16* __restrict__ d3, int n3) {
    int i = (blockIdx.x * 256 + threadIdx.x) * 4;
    const float* src;
    bf16* dst;
    if (i < n0) { src = s0; dst = d0; }
    else if (i < n0 + n1) { i -= n0; src = s1; dst = d1; }
    else if (i < n0 + n1 + n2) { i -= n0 + n1; src = s2; dst = d2; }
    else { i -= n0 + n1 + n2; if (i >= n3) return; src = s3; dst = d3; }
    float4 v = *(const float4*)(src + i);
    b4pack o;
    o.v[0] = (bf16)v.x; o.v[1] = (bf16)v.y; o.v[2] = (bf16)v.z; o.v[3] = (bf16)v.w;
    *(b4pack*)(dst + i) = o;
}

// ---------------- fused RMSNorm + RoPE ----------------
__global__ __launch_bounds__(256) void rmsnorm_rope_kernel(const float* __restrict__ x,
                                                           const float* __restrict__ scale,
                                                           bf16* __restrict__ xn,
                                                           bf16* __restrict__ rp, int T) {
    __shared__ float red[4];
    int row = blockIdx.x;
    int t = row % T;
    const float* xp = x + (size_t)row * D_MODEL;
    int tid = threadIdx.x;
    float4 xv = *(const float4*)(xp + tid * 4);
    float s = xv.x * xv.x + xv.y * xv.y + xv.z * xv.z + xv.w * xv.w;
    for (int off = 32; off; off >>= 1) s += __shfl_down(s, off);
    if ((tid & 63) == 0) red[tid >> 6] = s;
    __syncthreads();
    if (tid == 0) red[0] = red[0] + red[1] + red[2] + red[3];
    __syncthreads();
    float inv = rsqrtf(red[0] * (1.0f / D_MODEL) + 1e-6f);
    float4 sc = *(const float4*)(scale + tid * 4);
    float n0 = xv.x * inv * sc.x, n1 = xv.y * inv * sc.y;
    float n2 = xv.z * inv * sc.z, n3 = xv.w * inv * sc.w;
    b4pack pn;
    pn.v[0] = (bf16)n0; pn.v[1] = (bf16)n1; pn.v[2] = (bf16)n2; pn.v[3] = (bf16)n3;
    *(b4pack*)(xn + (size_t)row * D_MODEL + tid * 4) = pn;
    int p0 = 2 * tid;
    float th0 = expf(-0.2878231366242557f * (float)(p0 & 31));        // ln(10000)/32
    float th1 = expf(-0.2878231366242557f * (float)((p0 + 1) & 31));
    float s0, c0, s1, c1;
    sincosf((float)t * th0, &s0, &c0);
    sincosf((float)t * th1, &s1, &c1);
    b4pack pr;
    pr.v[0] = (bf16)(n0 * c0 - n1 * s0);
    pr.v[1] = (bf16)(n1 * c0 + n0 * s0);
    pr.v[2] = (bf16)(n2 * c1 - n3 * s1);
    pr.v[3] = (bf16)(n3 * c1 + n2 * s1);
    *(b4pack*)(rp + (size_t)row * D_MODEL + tid * 4) = pr;
}

// ---------------- RMSNorm only ----------------
__global__ __launch_bounds__(256) void rmsnorm_kernel(const float* __restrict__ x,
                                                      const float* __restrict__ scale,
                                                      bf16* __restrict__ out) {
    __shared__ float red[4];
    int row = blockIdx.x;
    const float* xp = x + (size_t)row * D_MODEL;
    bf16* op = out + (size_t)row * D_MODEL;
    int tid = threadIdx.x;
    float s = 0.f;
    for (int i = tid; i < D_MODEL; i += 256) { float v = xp[i]; s += v * v; }
    for (int off = 32; off; off >>= 1) s += __shfl_down(s, off);
    if ((tid & 63) == 0) red[tid >> 6] = s;
    __syncthreads();
    if (tid == 0) red[0] = red[0] + red[1] + red[2] + red[3];
    __syncthreads();
    float inv = rsqrtf(red[0] * (1.0f / D_MODEL) + 1e-6f);
    for (int i = tid; i < D_MODEL; i += 256) op[i] = (bf16)(xp[i] * inv * scale[i]);
}

// -------- bf16 MFMA GEMM, 128x128 tile, BK=64, 2-phase dbuf + counted vmcnt --------
// R5-verified. R6 lesson: never below 2 waves/SIMD for LDS-fed MFMA loops.
template <int ACT, int ADD, int OUT_BF16, int VT>
__global__ __launch_bounds__(256) void gemm_bf16(const bf16* __restrict__ A,
                                                 const bf16* __restrict__ A2, int splitN,
                                                 const bf16* __restrict__ W,
                                                 const float* __restrict__ bias,
                                                 float* __restrict__ Cf,
                                                 bf16* __restrict__ Cb,
                                                 bf16* __restrict__ Vtp, int Tlen,
                                                 int M, int N, int K) {
    __shared__ __align__(16) bf16 As[2][128 * 64];   // 2 x 16 KB
    __shared__ __align__(16) bf16 Bs[2][128 * 64];   // 2 x 16 KB
    int tid = threadIdx.x;
    int m0 = blockIdx.y * 128, n0 = blockIdx.x * 128;
    const bf16* Ag = (n0 < splitN) ? A : A2;

    int lane = tid & 63, w = tid >> 6;
    int wm = w >> 1, wn = w & 1;
    int lm = lane & 15, quad = lane >> 4;
    int lm7 = lm & 7;

    f32x4 acc[4][4];
#pragma unroll
    for (int i = 0; i < 4; i++)
#pragma unroll
        for (int j = 0; j < 4; j++)
#pragma unroll
            for (int r = 0; r < 4; r++) acc[i][j][r] = 0.f;

    int nt = K >> 6;

#pragma unroll
    for (int i = 0; i < 4; i++) {
        int cch = tid + 256 * i;
        int r = cch >> 3, cc = (cch & 7) ^ (r & 7);
        gld_lds16(Ag + (size_t)(m0 + r) * K + cc * 8, &As[0][0] + cch * 8);
        gld_lds16(W  + (size_t)(n0 + r) * K + cc * 8, &Bs[0][0] + cch * 8);
    }

    for (int t = 0; t < nt; ++t) {
        int cur = t & 1;
        if (t + 1 < nt) {
            int k0 = (t + 1) << 6;
            bf16* as = &As[cur ^ 1][0];
            bf16* bs = &Bs[cur ^ 1][0];
#pragma unroll
            for (int i = 0; i < 4; i++) {
                int cch = tid + 256 * i;
                int r = cch >> 3, cc = (cch & 7) ^ (r & 7);
                gld_lds16(Ag + (size_t)(m0 + r) * K + k0 + cc * 8, as + cch * 8);
                gld_lds16(W  + (size_t)(n0 + r) * K + k0 + cc * 8, bs + cch * 8);
            }
            asm volatile("s_waitcnt vmcnt(8)" ::: "memory");  // current tile landed
        } else {
            asm volatile("s_waitcnt vmcnt(0)" ::: "memory");  // epilogue drain
        }
        __builtin_amdgcn_s_barrier();

        const bf16* as = &As[cur][0];
        const bf16* bs = &Bs[cur][0];
        bf16x8 af[4][2], bfr[4][2];
#pragma unroll
        for (int i = 0; i < 4; i++) {
            int row = wm * 64 + i * 16 + lm;
#pragma unroll
            for (int h2 = 0; h2 < 2; h2++)
                af[i][h2] = *(const bf16x8*)&as[row * 64 + ((h2 * 4 + quad) ^ lm7) * 8];
        }
#pragma unroll
        for (int j = 0; j < 4; j++) {
            int row = wn * 64 + j * 16 + lm;
#pragma unroll
            for (int h2 = 0; h2 < 2; h2++)
                bfr[j][h2] = *(const bf16x8*)&bs[row * 64 + ((h2 * 4 + quad) ^ lm7) * 8];
        }
#pragma unroll
        for (int i = 0; i < 4; i++)
#pragma unroll
            for (int j = 0; j < 4; j++) {
                acc[i][j] = __builtin_amdgcn_mfma_f32_16x16x32_bf16(af[i][0], bfr[j][0], acc[i][j], 0, 0, 0);
                acc[i][j] = __builtin_amdgcn_mfma_f32_16x16x32_bf16(af[i][1], bfr[j][1], acc[i][j], 0, 0, 0);
            }
        asm volatile("" ::: "memory");   // keep ds_reads/MFMA above the barrier
        __builtin_amdgcn_s_barrier();    // protect current buffer from next stage
    }

    if (VT && n0 >= 2 * D_MODEL) {
#pragma unroll
        for (int j = 0; j < 4; j++) {
            int col = n0 + wn * 64 + j * 16 + lm;
            int dimg = col - 2 * D_MODEL;
            float bv = bias[col];
#pragma unroll
            for (int i = 0; i < 4; i++) {
                int row0 = m0 + wm * 64 + i * 16 + quad * 4;
                int bb = row0 / Tlen, t0 = row0 % Tlen;
                b4pack pk;
#pragma unroll
                for (int r = 0; r < 4; r++) pk.v[r] = (bf16)(acc[i][j][r] + bv);
                *(b4pack*)(Vtp + ((size_t)bb * D_MODEL + dimg) * Tlen + t0) = pk;
            }
        }
        return;
    }

#pragma unroll
    for (int j = 0; j < 4; j++) {
        int col = n0 + wn * 64 + j * 16 + lm;
        float bv = bias[col];
#pragma unroll
        for (int i = 0; i < 4; i++) {
#pragma unroll
            for (int r = 0; r < 4; r++) {
                int row = m0 + wm * 64 + i * 16 + quad * 4 + r;
                float v = acc[i][j][r] + bv;
                if (ACT == 1) v = v / (1.f + __expf(-v));
                size_t idx = (size_t)row * N + col;
                if (ADD) v += Cf[idx];
                if (OUT_BF16) Cb[idx] = (bf16)v;
                else Cf[idx] = v;
            }
        }
    }
}

// -- 128x128-tile GEMM, BK=64 2-phase, grid SPLIT-K + fp32 atomic epilogue --
// R7 post-mortem: skinny (64x128, 0.75 ds_read/MFMA) is ratio-bound at ~530 TF;
// the 128^2 tile's 64x64-per-wave shape (0.5 ratio) runs ~690 TF. For N=1024 a
// plain 128^2 grid is only 256 blocks (1/CU -> R6 lesson forbids); split-K x2
// restores 512 blocks = 2 blocks/CU (2 waves/SIMD) with 32-step K-chains.
// Epilogue: unsafeAtomicAdd into out (holds y; commutative; R1/R7-verified fp32
// atomic path, absmax unchanged). Split 0 adds bias. Bijective XCD swizzle,
// order n -> m -> split (W-chunk L2-resident per XCD).
template <int SPLIT>
__global__ __launch_bounds__(256) void gemm128_sk(const bf16* __restrict__ A,
                                                  const bf16* __restrict__ W,
                                                  const float* __restrict__ bias,
                                                  float* __restrict__ Cf,
                                                  int M, int N, int K) {
    __shared__ __align__(16) bf16 As[2][128 * 64];   // 2 x 16 KB
    __shared__ __align__(16) bf16 Bs[2][128 * 64];   // 2 x 16 KB
    int tid = threadIdx.x;

    int nblk = gridDim.x;
    int q = nblk >> 3;
    int swz = (blockIdx.x & 7) * q + (blockIdx.x >> 3);
    int nnb = N >> 7;
    int nb = swz % nnb;
    int rem = swz / nnb;
    int mblocks = M >> 7;
    int mb = rem % mblocks;
    int sp = rem / mblocks;
    int m0 = mb * 128, n0 = nb * 128;
    int kc = K / SPLIT;
    int kbeg = sp * kc;

    int lane = tid & 63, w = tid >> 6;
    int wm = w >> 1, wn = w & 1;
    int lm = lane & 15, quad = lane >> 4;
    int lm7 = lm & 7;

    f32x4 acc[4][4];
#pragma unroll
    for (int i = 0; i < 4; i++)
#pragma unroll
        for (int j = 0; j < 4; j++)
#pragma unroll
            for (int r = 0; r < 4; r++) acc[i][j][r] = 0.f;

    int nt = kc >> 6;

#pragma unroll
    for (int i = 0; i < 4; i++) {
        int cch = tid + 256 * i;
        int r = cch >> 3, cc = (cch & 7) ^ (r & 7);
        gld_lds16(A + (size_t)(m0 + r) * K + kbeg + cc * 8, &As[0][0] + cch * 8);
        gld_lds16(W + (size_t)(n0 + r) * K + kbeg + cc * 8, &Bs[0][0] + cch * 8);
    }

    for (int t = 0; t < nt; ++t) {
        int cur = t & 1;
        if (t + 1 < nt) {
            int k0 = kbeg + ((t + 1) << 6);
            bf16* as = &As[cur ^ 1][0];
            bf16* bs = &Bs[cur ^ 1][0];
#pragma unroll
            for (int i = 0; i < 4; i++) {
                int cch = tid + 256 * i;
                int r = cch >> 3, cc = (cch & 7) ^ (r & 7);
                gld_lds16(A + (size_t)(m0 + r) * K + k0 + cc * 8, as + cch * 8);
                gld_lds16(W + (size_t)(n0 + r) * K + k0 + cc * 8, bs + cch * 8);
            }
            asm volatile("s_waitcnt vmcnt(8)" ::: "memory");
        } else {
            asm volatile("s_waitcnt vmcnt(0)" ::: "memory");
        }
        __builtin_amdgcn_s_barrier();

        const bf16* as = &As[cur][0];
        const bf16* bs = &Bs[cur][0];
        bf16x8 af[4][2], bfr[4][2];
#pragma unroll
        for (int i = 0; i < 4; i++) {
            int row = wm * 64 + i * 16 + lm;
#pragma unroll
            for (int h2 = 0; h2 < 2; h2++)
                af[i][h2] = *(const bf16x8*)&as[row * 64 + ((h2 * 4 + quad) ^ lm7) * 8];
        }
#pragma unroll
        for (int j = 0; j < 4; j++) {
            int row = wn * 64 + j * 16 + lm;
#pragma unroll
            for (int h2 = 0; h2 < 2; h2++)
                bfr[j][h2] = *(const bf16x8*)&bs[row * 64 + ((h2 * 4 + quad) ^ lm7) * 8];
        }
#pragma unroll
        for (int i = 0; i < 4; i++)
#pragma unroll
            for (int j = 0; j < 4; j++) {
                acc[i][j] = __builtin_amdgcn_mfma_f32_16x16x32_bf16(af[i][0], bfr[j][0], acc[i][j], 0, 0, 0);
                acc[i][j] = __builtin_amdgcn_mfma_f32_16x16x32_bf16(af[i][1], bfr[j][1], acc[i][j], 0, 0, 0);
            }
        asm volatile("" ::: "memory");
        __builtin_amdgcn_s_barrier();
    }

#pragma unroll
    for (int j = 0; j < 4; j++) {
        int col = n0 + wn * 64 + j * 16 + lm;
        float bv = (sp == 0) ? bias[col] : 0.f;
#pragma unroll
        for (int i = 0; i < 4; i++) {
#pragma unroll
            for (int r = 0; r < 4; r++) {
                int row = m0 + wm * 64 + i * 16 + quad * 4 + r;
                unsafeAtomicAdd(Cf + (size_t)row * N + col, acc[i][j][r] + bv);
            }
        }
    }
}

// ------ skinny bf16 GEMM, 64x128 tile, BK=64, 2-phase dbuf + counted vmcnt ------
// R5-verified; used for step 5 (K=1024) where grid 512 = 2 blocks/CU.
template <int ADD>
__global__ __launch_bounds__(256) void gemm_bf16_skinny2(const bf16* __restrict__ A,
                                                         const bf16* __restrict__ W,
                                                         const float* __restrict__ bias,
                                                         float* __restrict__ Cf,
                                                         int M, int N, int K) {
    __shared__ __align__(16) bf16 As[2][64 * 64];    // 2 x 8 KB
    __shared__ __align__(16) bf16 Bs[2][128 * 64];   // 2 x 16 KB
    int tid = threadIdx.x;

    int nblk = gridDim.x;
    int q = nblk >> 3;
    int swz = (blockIdx.x & 7) * q + (blockIdx.x >> 3);
    int nb = swz & 7;          // N/128 == 8
    int mb = swz >> 3;
    int m0 = mb * 64, n0 = nb * 128;

    int lane = tid & 63, w = tid >> 6;
    int wm = w >> 1, wn = w & 1;          // 2x2 wave grid: 32 rows x 64 cols each
    int lm = lane & 15, quad = lane >> 4;
    int lm7 = lm & 7;

    int ar0 = tid >> 3, ac0 = (tid & 7) ^ (ar0 & 7);                 // A chunk 0
    int t1 = tid + 256;
    int ar1 = t1 >> 3, ac1 = (t1 & 7) ^ (ar1 & 7);                  // A chunk 1

    f32x4 acc[2][4];
#pragma unroll
    for (int i = 0; i < 2; i++)
#pragma unroll
        for (int j = 0; j < 4; j++)
#pragma unroll
            for (int r = 0; r < 4; r++) acc[i][j][r] = 0.f;

    int nt = K >> 6;

    {
        gld_lds16(A + (size_t)(m0 + ar0) * K + ac0 * 8, &As[0][0] + tid * 8);
        gld_lds16(A + (size_t)(m0 + ar1) * K + ac1 * 8, &As[0][0] + t1 * 8);
#pragma unroll
        for (int i = 0; i < 4; i++) {
            int c = tid + 256 * i;
            int r = c >> 3, cc = (c & 7) ^ (r & 7);
            gld_lds16(W + (size_t)(n0 + r) * K + cc * 8, &Bs[0][0] + c * 8);
        }
    }

    for (int t = 0; t < nt; ++t) {
        int cur = t & 1;
        if (t + 1 < nt) {
            int k0 = (t + 1) << 6;
            bf16* as = &As[cur ^ 1][0];
            bf16* bs = &Bs[cur ^ 1][0];
            gld_lds16(A + (size_t)(m0 + ar0) * K + k0 + ac0 * 8, as + tid * 8);
            gld_lds16(A + (size_t)(m0 + ar1) * K + k0 + ac1 * 8, as + t1 * 8);
#pragma unroll
            for (int i = 0; i < 4; i++) {
                int c = tid + 256 * i;
                int r = c >> 3, cc = (c & 7) ^ (r & 7);
                gld_lds16(W + (size_t)(n0 + r) * K + k0 + cc * 8, bs + c * 8);
            }
            asm volatile("s_waitcnt vmcnt(6)" ::: "memory");
        } else {
            asm volatile("s_waitcnt vmcnt(0)" ::: "memory");
        }
        __builtin_amdgcn_s_barrier();

        const bf16* as = &As[cur][0];
        const bf16* bs = &Bs[cur][0];
        bf16x8 af[2][2], bfr[4][2];
#pragma unroll
        for (int i = 0; i < 2; i++) {
            int row = wm * 32 + i * 16 + lm;
#pragma unroll
            for (int h = 0; h < 2; h++)
                af[i][h] = *(const bf16x8*)&as[row * 64 + ((h * 4 + quad) ^ lm7) * 8];
        }
#pragma unroll
        for (int j = 0; j < 4; j++) {
            int row = wn * 64 + j * 16 + lm;
#pragma unroll
            for (int h = 0; h < 2; h++)
                bfr[j][h] = *(const bf16x8*)&bs[row * 64 + ((h * 4 + quad) ^ lm7) * 8];
        }
#pragma unroll
        for (int i = 0; i < 2; i++)
#pragma unroll
            for (int j = 0; j < 4; j++) {
                acc[i][j] = __builtin_amdgcn_mfma_f32_16x16x32_bf16(af[i][0], bfr[j][0], acc[i][j], 0, 0, 0);
                acc[i][j] = __builtin_amdgcn_mfma_f32_16x16x32_bf16(af[i][1], bfr[j][1], acc[i][j], 0, 0, 0);
            }
        asm volatile("" ::: "memory");
        __builtin_amdgcn_s_barrier();
    }

#pragma unroll
    for (int j = 0; j < 4; j++) {
        int col = n0 + wn * 64 + j * 16 + lm;
        float bv = bias[col];
#pragma unroll
        for (int i = 0; i < 2; i++) {
#pragma unroll
            for (int r = 0; r < 4; r++) {
                int row = m0 + wm * 32 + i * 16 + quad * 4 + r;
                float v = acc[i][j][r] + bv;
                size_t idx = (size_t)row * N + col;
                if (ADD) v += Cf[idx];
                Cf[idx] = v;
            }
        }
    }
}

// ------- MFMA flash attention: pair-merged blocks, fixed-base softmax -------
__global__ __launch_bounds__(256, 2) void attn_mfma_kernel(const bf16* __restrict__ QKV,
                                                           const bf16* __restrict__ Vt,
                                                           bf16* __restrict__ Og, int T) {
    __shared__ __align__(16) bf16 Ks[2][2][64 * 64];   // [buf][sub] 32 KB
    __shared__ __align__(16) bf16 Vs[2][2][64 * 64];   // 32 KB
    __shared__ __align__(16) bf16 Ps[4 * 16 * 64];     // 8 KB, per-wave XOR-swizzled P
    const int ldq = 3 * D_MODEL;
    int bidx = blockIdx.x;
    int c = bidx & 7;               // XCD id; same-bh blocks share an XCD L2
    int rest = bidx >> 3;           // [0,64)
    int p = rest & 15;              // pair id
    int bhoct = rest >> 4;          // [0,4)
    int bh = bhoct * 8 + c;
    int qtA = 31 - p, qtB = p;      // qtA 16..31, qtB 0..15
    int h = bh & (NUM_HEADS - 1), b = bh / NUM_HEADS;
    int tid = threadIdx.x;
    int w = tid >> 6, lane = tid & 63;
    int lm = lane & 15, quad = lane >> 4;
    int qrowA = qtA * 64 + w * 16, qrowB = qtB * 64 + w * 16;

    int s0 = tid, s1 = tid + 256;
    int sr0 = s0 >> 3, sc0 = (s0 & 7) ^ (sr0 & 7);
    int sr1 = s1 >> 3, sc1 = (s1 & 7) ^ (sr1 & 7);

    const bf16* QpA = QKV + ((size_t)(b * T + qrowA + lm)) * ldq + h * HEAD_SIZE + quad * 8;
    bf16x8 qfA0 = *(const bf16x8*)QpA;
    bf16x8 qfA1 = *(const bf16x8*)(QpA + 32);
    const bf16* QpB = QKV + ((size_t)(b * T + qrowB + lm)) * ldq + h * HEAD_SIZE + quad * 8;
    bf16x8 qfB0 = *(const bf16x8*)QpB;
    bf16x8 qfB1 = *(const bf16x8*)(QpB + 32);

    const bf16* Kbase = QKV + ((size_t)b * T) * ldq + D_MODEL + h * HEAD_SIZE;
    const bf16* Vbase = Vt + ((size_t)b * D_MODEL + h * HEAD_SIZE) * T;
    const float C = 0.1803368801111204f;  // 0.125 * log2(e)
    bf16* PsW = Ps + w * 16 * 64;
    int lm7 = lm & 7;

    bf16x8 ones;
#pragma unroll
    for (int i = 0; i < 8; i++) ones[i] = (bf16)1.0f;

    f32x4 oA[4], oB[4], laccA, laccB;
#pragma unroll
    for (int r = 0; r < 4; r++) {
        oA[r] = (f32x4){0.f, 0.f, 0.f, 0.f};
        oB[r] = (f32x4){0.f, 0.f, 0.f, 0.f};
        laccA[r] = 0.f; laccB[r] = 0.f;
    }

    int nktA = (qtA + 2) >> 1;   // 9..16
    int nktB = (qtB + 2) >> 1;   // 1..8 (always < nktA)

    auto stage = [&](int buf, int k0) {
        gld_lds16(Kbase + (size_t)(k0 + sr0) * ldq + sc0 * 8, &Ks[buf][0][0] + s0 * 8);
        gld_lds16(Kbase + (size_t)(k0 + sr1) * ldq + sc1 * 8, &Ks[buf][0][0] + s1 * 8);
        gld_lds16(Kbase + (size_t)(k0 + 64 + sr0) * ldq + sc0 * 8, &Ks[buf][1][0] + s0 * 8);
        gld_lds16(Kbase + (size_t)(k0 + 64 + sr1) * ldq + sc1 * 8, &Ks[buf][1][0] + s1 * 8);
        gld_lds16(Vbase + (size_t)sr0 * T + k0 + sc0 * 8, &Vs[buf][0][0] + s0 * 8);
        gld_lds16(Vbase + (size_t)sr1 * T + k0 + sc1 * 8, &Vs[buf][0][0] + s1 * 8);
        gld_lds16(Vbase + (size_t)sr0 * T + k0 + 64 + sc0 * 8, &Vs[buf][1][0] + s0 * 8);
        gld_lds16(Vbase + (size_t)sr1 * T + k0 + 64 + sc1 * 8, &Vs[buf][1][0] + s1 * 8);
    };

    auto run_tile = [&](int cur, int k0, bf16x8 qf0, bf16x8 qf1, int qrow0,
                        f32x4 (&o)[4], f32x4& lacc, bool lastmask) {
        f32x4 sa[2][4];
        __builtin_amdgcn_s_setprio(1);
#pragma unroll
        for (int u = 0; u < 2; u++) {
            const bf16* Ksu = &Ks[cur][u][0];
#pragma unroll
            for (int jb = 0; jb < 4; jb++) {
                int n = jb * 16 + lm;
                bf16x8 kf0 = *(const bf16x8*)&Ksu[(n * 8 + (quad ^ lm7)) * 8];
                bf16x8 kf1 = *(const bf16x8*)&Ksu[(n * 8 + ((quad + 4) ^ lm7)) * 8];
                f32x4 a = {0.f, 0.f, 0.f, 0.f};
                a = __builtin_amdgcn_mfma_f32_16x16x32_bf16(qf0, kf0, a, 0, 0, 0);
                a = __builtin_amdgcn_mfma_f32_16x16x32_bf16(qf1, kf1, a, 0, 0, 0);
                sa[u][jb] = a;
            }
        }
        __builtin_amdgcn_s_setprio(0);
        if (lastmask) {
#pragma unroll
            for (int u = 0; u < 2; u++)
#pragma unroll
                for (int jb = 0; jb < 4; jb++)
#pragma unroll
                    for (int r = 0; r < 4; r++)
                        if (k0 + u * 64 + jb * 16 + lm > qrow0 + quad * 4 + r)
                            sa[u][jb][r] = -3.0e38f;
        }
        // fixed-base softmax: p = exp2(s*C); masked -> exp2(-huge) == 0
#pragma unroll
        for (int u = 0; u < 2; u++) {
            const bf16* Vsu = &Vs[cur][u][0];
#pragma unroll
            for (int jb = 0; jb < 4; jb++) {
                int g = jb * 2 + (lm >> 3);
#pragma unroll
                for (int r = 0; r < 4; r++) {
                    int row = quad * 4 + r;
                    float pv = exp2f(sa[u][jb][r] * C);
                    PsW[row * 64 + ((g ^ (row & 7)) * 8) + lm7] = (bf16)pv;
                }
            }
            bf16x8 pf0 = *(const bf16x8*)&PsW[lm * 64 + ((quad ^ lm7) * 8)];
            bf16x8 pf1 = *(const bf16x8*)&PsW[lm * 64 + (((quad + 4) ^ lm7) * 8)];
            __builtin_amdgcn_s_setprio(1);
#pragma unroll
            for (int db = 0; db < 4; db++) {
                int n = db * 16 + lm;
                bf16x8 vf0 = *(const bf16x8*)&Vsu[(n * 8 + (quad ^ lm7)) * 8];
                bf16x8 vf1 = *(const bf16x8*)&Vsu[(n * 8 + ((quad + 4) ^ lm7)) * 8];
                o[db] = __builtin_amdgcn_mfma_f32_16x16x32_bf16(pf0, vf0, o[db], 0, 0, 0);
                o[db] = __builtin_amdgcn_mfma_f32_16x16x32_bf16(pf1, vf1, o[db], 0, 0, 0);
            }
            // row-sum of P on the matrix pipe: l += P @ ones
            lacc = __builtin_amdgcn_mfma_f32_16x16x32_bf16(pf0, ones, lacc, 0, 0, 0);
            lacc = __builtin_amdgcn_mfma_f32_16x16x32_bf16(pf1, ones, lacc, 0, 0, 0);
            __builtin_amdgcn_s_setprio(0);
        }
    };

    stage(0, 0);   // prologue: round 0 -> buffer 0
    for (int kt = 0; kt < nktA; kt++) {
        int cur = kt & 1;
        if (kt + 1 < nktA) {
            stage(cur ^ 1, (kt + 1) * 128);
            asm volatile("s_waitcnt vmcnt(8)" ::: "memory");  // round kt landed
        } else {
            asm volatile("s_waitcnt vmcnt(0)" ::: "memory");
        }
        __builtin_amdgcn_s_barrier();
        asm volatile("" ::: "memory");
        int k0 = kt * 128;
        run_tile(cur, k0, qfA0, qfA1, qrowA, oA, laccA, kt == nktA - 1);
        if (kt < nktB)
            run_tile(cur, k0, qfB0, qfB1, qrowB, oB, laccB, kt == nktB - 1);
        asm volatile("" ::: "memory");
        __builtin_amdgcn_s_barrier();   // protect buffers from next stage
    }

    // epilogue: O / l -> bf16, both tiles
    {
        float inv[4];
#pragma unroll
        for (int r = 0; r < 4; r++) inv[r] = 1.f / laccA[r];
        bf16* Ob = Og + ((size_t)(b * T + qrowA + quad * 4)) * D_MODEL + h * HEAD_SIZE + lm;
#pragma unroll
        for (int r = 0; r < 4; r++)
#pragma unroll
            for (int db = 0; db < 4; db++)
                Ob[(size_t)r * D_MODEL + db * 16] = (bf16)(oA[db][r] * inv[r]);
    }
    {
        float inv[4];
#pragma unroll
        for (int r = 0; r < 4; r++) inv[r] = 1.f / laccB[r];
        bf16* Ob = Og + ((size_t)(b * T + qrowB + quad * 4)) * D_MODEL + h * HEAD_SIZE + lm;
#pragma unroll
        for (int r = 0; r < 4; r++)
#pragma unroll
            for (int db = 0; db < 4; db++)
                Ob[(size_t)r * D_MODEL + db * 16] = (bf16)(oB[db][r] * inv[r]);
    }
}

extern "C" void kernel_launch(void* const* d_in, const int* in_sizes, int n_in,
                              void* d_out, int out_size, void* d_ws, size_t ws_size,
                              hipStream_t stream) {
    const float* x          = (const float*)d_in[0];
    const float* rms_scale  = (const float*)d_in[1];
    const float* in_proj_w  = (const float*)d_in[2];
    const float* in_proj_b  = (const float*)d_in[3];
    const float* out_proj_w = (const float*)d_in[4];
    const float* out_proj_b = (const float*)d_in[5];
    const float* w1         = (const float*)d_in[6];
    const float* b1         = (const float*)d_in[7];
    const float* w2         = (const float*)d_in[8];
    const float* b2         = (const float*)d_in[9];
    float* out = (float*)d_out;

    const int rows = in_sizes[0] / D_MODEL;  // 4096
    const int T = SEQ_T;
    const int B = rows / T;
    const int D = D_MODEL;

    bf16* inwb  = (bf16*)d_ws;                       // 3M
    bf16* outwb = inwb + (size_t)3 * D * D;          // 1M
    bf16* w1b   = outwb + (size_t)D * D;             // 4M
    bf16* w2b   = w1b + (size_t)4 * D * D;           // 4M
    bf16* XNb   = w2b + (size_t)4 * D * D;           // rows*D (reused as CTXb)
    bf16* RPb   = XNb + (size_t)rows * D;            // rows*D (reused as YNb)
    bf16* QKV   = RPb + (size_t)rows * D;            // rows*3D (H1b spans rows*4D)
    bf16* Vt    = QKV + (size_t)rows * 3 * D;        // rows*D  (tail of H1b region)
    bf16* CTXb  = XNb;
    bf16* YNb   = RPb;
    bf16* H1b   = QKV;

    // 0. cast all weights to bf16 (one kernel)
    {
        int n0 = 3 * D * D, n1 = D * D, n2 = 4 * D * D, n3 = 4 * D * D;
        int tot4 = (n0 + n1 + n2 + n3) / 4;
        cast_all_weights<<<(tot4 + 255) / 256, 256, 0, stream>>>(
            in_proj_w, inwb, n0, out_proj_w, outwb, n1, w1, w1b, n2, w2, w2b, n3);
    }
    // 1+2. fused rmsnorm + rope
    rmsnorm_rope_kernel<<<rows, 256, 0, stream>>>(x, rms_scale, XNb, RPb, T);
    // 3. fused QKV projection; Q/K -> QKV buffer, V -> Vt (transposed)
    {
        dim3 g(3 * D / 128, rows / 128);
        gemm_bf16<0, 0, 1, 1><<<g, 256, 0, stream>>>(RPb, XNb, 2 * D, inwb, in_proj_b,
                                                     nullptr, QKV, Vt, T, rows, 3 * D, D);
    }
    // 4. attention -> CTXb (bf16): 512 pair-merged balanced blocks, dbuf pipeline
    attn_mfma_kernel<<<B * NUM_HEADS * (T / 128), 256, 0, stream>>>(QKV, Vt, CTXb, T);
    // 5. y = CTXb @ out_proj^T + b -> d_out (fp32), 2-phase skinny (512 blocks)
    {
        int nblk = (D / 128) * (rows / 64);
        gemm_bf16_skinny2<0><<<nblk, 256, 0, stream>>>(CTXb, outwb, out_proj_b, out,
                                                       rows, D, D);
    }
    // 6. yn = rmsnorm(y) -> bf16
    rmsnorm_kernel<<<rows, 256, 0, stream>>>(out, rms_scale, YNb);
    // 7. H1b = silu(yn @ w1^T + b1) (bf16)
    {
        dim3 g(4 * D / 128, rows / 128);
        gemm_bf16<1, 0, 1, 0><<<g, 256, 0, stream>>>(YNb, YNb, 4 * D, w1b, b1,
                                                     nullptr, H1b, nullptr, 1, rows, 4 * D, D);
    }
    // 8. out += H1b @ w2^T + b2 (split 0 adds bias), 128^2-tile split-K x2 atomic
    {
        int nblk = 2 * (rows / 128) * (D / 128);   // 512 blocks = 2/CU
        gemm128_sk<2><<<nblk, 256, 0, stream>>>(H1b, w2b, b2, out, rows, D, 4 * D);
    }
}